// Round 1
// baseline (373.958 us; speedup 1.0000x reference)
//
#include <hip/hip_runtime.h>
#include <hip/hip_bf16.h>

typedef __bf16 bf16x8 __attribute__((ext_vector_type(8)));
typedef float f32x4 __attribute__((ext_vector_type(4)));
typedef unsigned short ushort_t;

static __device__ __forceinline__ bf16x8 cvt8(const float4& a, const float4& b) {
    bf16x8 r;
    r[0] = (__bf16)a.x; r[1] = (__bf16)a.y; r[2] = (__bf16)a.z; r[3] = (__bf16)a.w;
    r[4] = (__bf16)b.x; r[5] = (__bf16)b.y; r[6] = (__bf16)b.z; r[7] = (__bf16)b.w;
    return r;
}
static __device__ __forceinline__ bf16x8 load8(const float* p) {
    const float4* q = (const float4*)p;
    float4 a = q[0], b = q[1];
    return cvt8(a, b);
}

// ---------------- zero workspace ----------------
__global__ void zero_ws(float4* p, int n4) {
    int idx = blockIdx.x * blockDim.x + threadIdx.x;
    int stride = gridDim.x * blockDim.x;
    float4 z = make_float4(0.f, 0.f, 0.f, 0.f);
    for (; idx < n4; idx += stride) p[idx] = z;
}

// ---------------- pack weights into MFMA B-fragment order (bf16) ----------------
// B-frag layout for mfma_f32_16x16x32_bf16: lane l holds B[k][n] with
// n = ntile*16 + (l&15), k = kstep*32 + (l>>4)*8 + i   (i = 0..7)
// stored at wf[(frag*64 + l)*8 + i]
__global__ void pack_weights(const float* __restrict__ We1, const float* __restrict__ We2,
                             const float* __restrict__ Wn1, const float* __restrict__ Wn2,
                             ushort_t* __restrict__ wf_e1, ushort_t* __restrict__ wf_e2,
                             ushort_t* __restrict__ wf_n1, ushort_t* __restrict__ wf_n2) {
    int tid = threadIdx.x;
    // W_e1 [128][64]: nt=4, kt=4, frag f = t*4+s  -> 16 frags
    for (int idx = tid; idx < 16 * 512; idx += 256) {
        int f = idx >> 9, rem = idx & 511, l = rem >> 3, i = rem & 7;
        int t = f >> 2, s = f & 3;
        int k = s * 32 + (l >> 4) * 8 + i, n = t * 16 + (l & 15);
        wf_e1[idx] = __builtin_bit_cast(ushort_t, (__bf16)We1[k * 64 + n]);
    }
    // W_e2 [64][32]: nt=2, kt=2, frag f = t*2+s -> 4 frags
    for (int idx = tid; idx < 4 * 512; idx += 256) {
        int f = idx >> 9, rem = idx & 511, l = rem >> 3, i = rem & 7;
        int t = f >> 1, s = f & 1;
        int k = s * 32 + (l >> 4) * 8 + i, n = t * 16 + (l & 15);
        wf_e2[idx] = __builtin_bit_cast(ushort_t, (__bf16)We2[k * 32 + n]);
    }
    // W_n1 [96][64]: nt=4, kt=3, frag f = t*3+s -> 12 frags
    for (int idx = tid; idx < 12 * 512; idx += 256) {
        int f = idx >> 9, rem = idx & 511, l = rem >> 3, i = rem & 7;
        int t = f / 3, s = f - t * 3;
        int k = s * 32 + (l >> 4) * 8 + i, n = t * 16 + (l & 15);
        wf_n1[idx] = __builtin_bit_cast(ushort_t, (__bf16)Wn1[k * 64 + n]);
    }
    // W_n2 [64][32]: nt=2, kt=2 -> 4 frags
    for (int idx = tid; idx < 4 * 512; idx += 256) {
        int f = idx >> 9, rem = idx & 511, l = rem >> 3, i = rem & 7;
        int t = f >> 1, s = f & 1;
        int k = s * 32 + (l >> 4) * 8 + i, n = t * 16 + (l & 15);
        wf_n2[idx] = __builtin_bit_cast(ushort_t, (__bf16)Wn2[k * 32 + n]);
    }
}

// ---------------- edge update + scatters ----------------
__launch_bounds__(256)
__global__ void edge_kernel(
    const float* __restrict__ edge_feat, const float* __restrict__ node_feat,
    const float* __restrict__ g_repr, const int* __restrict__ src,
    const int* __restrict__ dst, const int* __restrict__ e2g,
    const ushort_t* __restrict__ wf1, const ushort_t* __restrict__ wf2,
    const float* __restrict__ b1, const float* __restrict__ b2,
    float* __restrict__ e_out, float* __restrict__ h_node,
    float* __restrict__ e_comb, int E) {
    __shared__ float lds_h[4][16][68];   // per-wave hidden transpose buffer (padded stride)
    __shared__ float lds_ec[256];        // 8 graphs x 32 cols bins
    int tid = threadIdx.x;
    lds_ec[tid] = 0.f;
    __syncthreads();
    int lane = tid & 63, wid = tid >> 6;
    int lo = lane & 15, kg = lane >> 4;

    const bf16x8* pf1 = (const bf16x8*)wf1;
    const bf16x8* pf2 = (const bf16x8*)wf2;
    bf16x8 w1[4][4], w2[2][2];
#pragma unroll
    for (int t = 0; t < 4; ++t)
#pragma unroll
        for (int s = 0; s < 4; ++s) w1[t][s] = pf1[(t * 4 + s) * 64 + lane];
#pragma unroll
    for (int t = 0; t < 2; ++t)
#pragma unroll
        for (int s = 0; s < 2; ++s) w2[t][s] = pf2[(t * 2 + s) * 64 + lane];
    float bias1[4], bias2[2];
#pragma unroll
    for (int t = 0; t < 4; ++t) bias1[t] = b1[t * 16 + lo];
#pragma unroll
    for (int t = 0; t < 2; ++t) bias2[t] = b2[t * 16 + lo];

    int nTiles = E >> 4;
    int gw = gridDim.x * 4;
    for (int tile = blockIdx.x * 4 + wid; tile < nTiles; tile += gw) {
        int m0 = tile << 4;
        int arow = m0 + lo;
        int si = src[arow], di = dst[arow], gi = e2g[arow];
        bf16x8 a[4];
        a[0] = load8(edge_feat + (size_t)arow * 32 + kg * 8);
        a[1] = load8(node_feat + (size_t)si * 32 + kg * 8);
        a[2] = load8(node_feat + (size_t)di * 32 + kg * 8);
        a[3] = load8(g_repr + (size_t)gi * 32 + kg * 8);
#pragma unroll
        for (int t = 0; t < 4; ++t) {
            f32x4 acc = {0.f, 0.f, 0.f, 0.f};
#pragma unroll
            for (int s = 0; s < 4; ++s)
                acc = __builtin_amdgcn_mfma_f32_16x16x32_bf16(a[s], w1[t][s], acc, 0, 0, 0);
            int col = t * 16 + lo;
#pragma unroll
            for (int r = 0; r < 4; ++r)
                lds_h[wid][kg * 4 + r][col] = fmaxf(acc[r] + bias1[t], 0.f);
        }
        bf16x8 ha[2];
#pragma unroll
        for (int s = 0; s < 2; ++s) {
            const float* p = &lds_h[wid][lo][s * 32 + kg * 8];
            const float4* q = (const float4*)p;
            ha[s] = cvt8(q[0], q[1]);
        }
        int drow[4], grow[4];
#pragma unroll
        for (int r = 0; r < 4; ++r) {
            int em = m0 + kg * 4 + r;
            drow[r] = dst[em];
            grow[r] = e2g[em];
        }
#pragma unroll
        for (int t = 0; t < 2; ++t) {
            f32x4 acc = {0.f, 0.f, 0.f, 0.f};
#pragma unroll
            for (int s = 0; s < 2; ++s)
                acc = __builtin_amdgcn_mfma_f32_16x16x32_bf16(ha[s], w2[t][s], acc, 0, 0, 0);
            int col = t * 16 + lo;
#pragma unroll
            for (int r = 0; r < 4; ++r) {
                float v = acc[r] + bias2[t];
                int em = m0 + kg * 4 + r;
                e_out[(size_t)em * 32 + col] = v;
                atomicAdd(&h_node[(size_t)drow[r] * 32 + col], v);
                atomicAdd(&lds_ec[grow[r] * 32 + col], v);
            }
        }
    }
    __syncthreads();
    atomicAdd(&e_comb[tid], lds_ec[tid]);
}

// ---------------- node update ----------------
__launch_bounds__(256)
__global__ void node_kernel(
    const float* __restrict__ node_feat, const float* __restrict__ g_repr,
    const int* __restrict__ n2g, const float* __restrict__ h_node,
    const ushort_t* __restrict__ wf1, const ushort_t* __restrict__ wf2,
    const float* __restrict__ b1, const float* __restrict__ b2,
    float* __restrict__ n_out, float* __restrict__ n_comb, int N) {
    __shared__ float lds_h[4][16][68];
    __shared__ float lds_nc[256];
    int tid = threadIdx.x;
    lds_nc[tid] = 0.f;
    __syncthreads();
    int lane = tid & 63, wid = tid >> 6;
    int lo = lane & 15, kg = lane >> 4;

    const bf16x8* pf1 = (const bf16x8*)wf1;
    const bf16x8* pf2 = (const bf16x8*)wf2;
    bf16x8 w1[4][3], w2[2][2];
#pragma unroll
    for (int t = 0; t < 4; ++t)
#pragma unroll
        for (int s = 0; s < 3; ++s) w1[t][s] = pf1[(t * 3 + s) * 64 + lane];
#pragma unroll
    for (int t = 0; t < 2; ++t)
#pragma unroll
        for (int s = 0; s < 2; ++s) w2[t][s] = pf2[(t * 2 + s) * 64 + lane];
    float bias1[4], bias2[2];
#pragma unroll
    for (int t = 0; t < 4; ++t) bias1[t] = b1[t * 16 + lo];
#pragma unroll
    for (int t = 0; t < 2; ++t) bias2[t] = b2[t * 16 + lo];

    int nTiles = N >> 4;
    int gw = gridDim.x * 4;
    for (int tile = blockIdx.x * 4 + wid; tile < nTiles; tile += gw) {
        int m0 = tile << 4;
        int arow = m0 + lo;
        int gi = n2g[arow];
        bf16x8 a[3];
        a[0] = load8(node_feat + (size_t)arow * 32 + kg * 8);
        a[1] = load8(h_node + (size_t)arow * 32 + kg * 8);
        a[2] = load8(g_repr + (size_t)gi * 32 + kg * 8);
#pragma unroll
        for (int t = 0; t < 4; ++t) {
            f32x4 acc = {0.f, 0.f, 0.f, 0.f};
#pragma unroll
            for (int s = 0; s < 3; ++s)
                acc = __builtin_amdgcn_mfma_f32_16x16x32_bf16(a[s], w1[t][s], acc, 0, 0, 0);
            int col = t * 16 + lo;
#pragma unroll
            for (int r = 0; r < 4; ++r)
                lds_h[wid][kg * 4 + r][col] = fmaxf(acc[r] + bias1[t], 0.f);
        }
        bf16x8 ha[2];
#pragma unroll
        for (int s = 0; s < 2; ++s) {
            const float* p = &lds_h[wid][lo][s * 32 + kg * 8];
            const float4* q = (const float4*)p;
            ha[s] = cvt8(q[0], q[1]);
        }
        int grow[4];
#pragma unroll
        for (int r = 0; r < 4; ++r) grow[r] = n2g[m0 + kg * 4 + r];
#pragma unroll
        for (int t = 0; t < 2; ++t) {
            f32x4 acc = {0.f, 0.f, 0.f, 0.f};
#pragma unroll
            for (int s = 0; s < 2; ++s)
                acc = __builtin_amdgcn_mfma_f32_16x16x32_bf16(ha[s], w2[t][s], acc, 0, 0, 0);
            int col = t * 16 + lo;
#pragma unroll
            for (int r = 0; r < 4; ++r) {
                float v = acc[r] + bias2[t];
                int em = m0 + kg * 4 + r;
                n_out[(size_t)em * 32 + col] = v;
                atomicAdd(&lds_nc[grow[r] * 32 + col], v);
            }
        }
    }
    __syncthreads();
    atomicAdd(&n_comb[tid], lds_nc[tid]);
}

// ---------------- global update (tiny, exact fp32) ----------------
__global__ void global_kernel(const float* __restrict__ g_repr, const float* __restrict__ e_comb,
                              const float* __restrict__ n_comb, const float* __restrict__ Wu1,
                              const float* __restrict__ bu1, const float* __restrict__ Wu2,
                              const float* __restrict__ bu2, float* __restrict__ g_out) {
    __shared__ float u[8][96];
    __shared__ float hh[8][64];
    int tid = threadIdx.x;
    {
        int i = tid >> 5, c = tid & 31;
        u[i][c] = n_comb[tid];
        u[i][32 + c] = e_comb[tid];
        u[i][64 + c] = g_repr[tid];
    }
    __syncthreads();
    for (int idx = tid; idx < 512; idx += 256) {
        int i = idx >> 6, j = idx & 63;
        float s = bu1[j];
        for (int k = 0; k < 96; ++k) s += u[i][k] * Wu1[k * 64 + j];
        hh[i][j] = fmaxf(s, 0.f);
    }
    __syncthreads();
    {
        int i = tid >> 5, c = tid & 31;
        float s = bu2[c];
        for (int j = 0; j < 64; ++j) s += hh[i][j] * Wu2[j * 32 + c];
        g_out[tid] = s;
    }
}

extern "C" void kernel_launch(void* const* d_in, const int* in_sizes, int n_in,
                              void* d_out, int out_size, void* d_ws, size_t ws_size,
                              hipStream_t stream) {
    const float* edge_feat = (const float*)d_in[0];
    const float* node_feat = (const float*)d_in[1];
    const float* g_repr = (const float*)d_in[2];
    const int* src = (const int*)d_in[3];
    const int* dst = (const int*)d_in[4];
    const int* n2g = (const int*)d_in[5];
    const int* e2g = (const int*)d_in[6];
    const float* We1 = (const float*)d_in[7];
    const float* be1 = (const float*)d_in[8];
    const float* We2 = (const float*)d_in[9];
    const float* be2 = (const float*)d_in[10];
    const float* Wn1 = (const float*)d_in[11];
    const float* bn1 = (const float*)d_in[12];
    const float* Wn2 = (const float*)d_in[13];
    const float* bn2 = (const float*)d_in[14];
    const float* Wu1 = (const float*)d_in[15];
    const float* bu1 = (const float*)d_in[16];
    const float* Wu2 = (const float*)d_in[17];
    const float* bu2 = (const float*)d_in[18];

    int E = in_sizes[3];          // 800000
    int N = in_sizes[1] / 32;     // 50000

    float* out = (float*)d_out;
    float* e_out = out;
    float* n_out = out + (size_t)E * 32;
    float* g_out = out + (size_t)(E + N) * 32;

    char* ws = (char*)d_ws;
    float* h_node = (float*)ws;                                // N*32 floats
    float* e_comb = (float*)(ws + (size_t)N * 32 * 4);         // 256 floats
    float* n_comb = e_comb + 256;                              // 256 floats
    ushort_t* wf_e1 = (ushort_t*)(n_comb + 256);               // 8192
    ushort_t* wf_e2 = wf_e1 + 8192;                            // 2048
    ushort_t* wf_n1 = wf_e2 + 2048;                            // 6144
    ushort_t* wf_n2 = wf_n1 + 6144;                            // 2048

    int n4 = (N * 32 + 512) / 4;  // h_node + e_comb + n_comb, in float4s
    zero_ws<<<512, 256, 0, stream>>>((float4*)ws, n4);
    pack_weights<<<1, 256, 0, stream>>>(We1, We2, Wn1, Wn2, wf_e1, wf_e2, wf_n1, wf_n2);
    edge_kernel<<<1280, 256, 0, stream>>>(edge_feat, node_feat, g_repr, src, dst, e2g,
                                          wf_e1, wf_e2, be1, be2, e_out, h_node, e_comb, E);
    node_kernel<<<256, 256, 0, stream>>>(node_feat, g_repr, n2g, h_node,
                                         wf_n1, wf_n2, bn1, bn2, n_out, n_comb, N);
    global_kernel<<<1, 256, 0, stream>>>(g_repr, e_comb, n_comb, Wu1, bu1, Wu2, bu2, g_out);
}